// Round 1
// baseline (221.993 us; speedup 1.0000x reference)
//
#include <hip/hip_runtime.h>

#define SEQ_LEN 16384
#define ENC_H   2048
#define DEC_H   2048
#define NB_SC   1024                 // k_scores blocks: 16 rows each, 4 rows per wave
#define WTHR    1e-9f                // skip threshold; err <= 16384*1e-9*max|enc| ~ 1e-4
#define CAP     256                  // survivor-list capacity (expected ~5-10 survivors)

// ---------------- K1: v[b] = W[b,:] . dec ; one block per row ----------------
// 2048 blocks x 256 thr -> 8 blocks/CU, 32 waves/CU: latency fully hidden
__global__ __launch_bounds__(256) void k_wv(const float* __restrict__ W,
                                            const float* __restrict__ dec,
                                            float* __restrict__ v) {
    __shared__ float sred[4];
    const int b = blockIdx.x, t = threadIdx.x, lane = t & 63, wave = t >> 6;
    const float4* Wr = (const float4*)(W + (size_t)b * DEC_H);
    const float4* d4 = (const float4*)dec;
    const float4 a0 = Wr[t], a1 = Wr[t + 256];             // 2 independent loads
    const float4 d0 = d4[t], d1 = d4[t + 256];
    float acc = a0.x * d0.x + a0.y * d0.y + a0.z * d0.z + a0.w * d0.w
              + a1.x * d1.x + a1.y * d1.y + a1.z * d1.z + a1.w * d1.w;
#pragma unroll
    for (int off = 32; off > 0; off >>= 1) acc += __shfl_down(acc, off, 64);
    if (lane == 0) sred[wave] = acc;
    __syncthreads();
    if (t == 0) v[b] = sred[0] + sred[1] + sred[2] + sred[3];
}

// ------- K2: scores + per-block online-softmax state; 4 rows per wave, batched -------
__global__ __launch_bounds__(256) void k_scores(const float* __restrict__ enc,
                                                const float* __restrict__ v,
                                                float* __restrict__ scores,
                                                float* __restrict__ bmax,
                                                float* __restrict__ bsum) {
    __shared__ float4 sv[ENC_H / 4];   // 8 KB
    __shared__ float smax[4], ssum[4];
    const int t = threadIdx.x, lane = t & 63, wave = t >> 6;
    const float4* v4 = (const float4*)v;
    for (int i = t; i < ENC_H / 4; i += 256) sv[i] = v4[i];
    __syncthreads();

    const int r0 = blockIdx.x * 16 + wave * 4;             // 4 consecutive rows per wave
    const float4* e0 = (const float4*)(enc + (size_t)(r0 + 0) * ENC_H);
    const float4* e1 = (const float4*)(enc + (size_t)(r0 + 1) * ENC_H);
    const float4* e2 = (const float4*)(enc + (size_t)(r0 + 2) * ENC_H);
    const float4* e3 = (const float4*)(enc + (size_t)(r0 + 3) * ENC_H);
    float a0 = 0.f, a1 = 0.f, a2 = 0.f, a3 = 0.f;
#pragma unroll
    for (int k = 0; k < ENC_H / 4 / 64; ++k) {             // 8 iters; 4 indep loads each
        const int i = k * 64 + lane;
        const float4 w = sv[i];
        const float4 x0 = e0[i], x1 = e1[i], x2 = e2[i], x3 = e3[i];
        a0 += x0.x * w.x + x0.y * w.y + x0.z * w.z + x0.w * w.w;
        a1 += x1.x * w.x + x1.y * w.y + x1.z * w.z + x1.w * w.w;
        a2 += x2.x * w.x + x2.y * w.y + x2.z * w.z + x2.w * w.w;
        a3 += x3.x * w.x + x3.y * w.y + x3.z * w.z + x3.w * w.w;
    }
#pragma unroll
    for (int off = 32; off > 0; off >>= 1) {               // 4 indep reduce chains
        a0 += __shfl_down(a0, off, 64);
        a1 += __shfl_down(a1, off, 64);
        a2 += __shfl_down(a2, off, 64);
        a3 += __shfl_down(a3, off, 64);
    }
    if (lane == 0) {
        scores[r0 + 0] = a0; scores[r0 + 1] = a1;
        scores[r0 + 2] = a2; scores[r0 + 3] = a3;
        const float m = fmaxf(fmaxf(a0, a1), fmaxf(a2, a3));
        smax[wave] = m;
        ssum[wave] = __expf(a0 - m) + __expf(a1 - m) + __expf(a2 - m) + __expf(a3 - m);
    }
    __syncthreads();
    if (t == 0) {
        const float bm = fmaxf(fmaxf(smax[0], smax[1]), fmaxf(smax[2], smax[3]));
        float bs = 0.f;
#pragma unroll
        for (int w2 = 0; w2 < 4; ++w2) bs += ssum[w2] * __expf(smax[w2] - bm);
        bmax[blockIdx.x] = bm; bsum[blockIdx.x] = bs;
    }
}

// ------- K3: single-block finalize: global softmax stats + sparse context -------
// One block computes m, 1/S once (instead of 1024 blocks redundantly), gathers the
// few rows with weight > WTHR into LDS, accumulates context, writes out directly
// (no atomics, no pre-zeroed out buffer).
__global__ __launch_bounds__(256) void k_finalize(const float* __restrict__ enc,
                                                  const float* __restrict__ scores,
                                                  const float* __restrict__ bmax,
                                                  const float* __restrict__ bsum,
                                                  float* __restrict__ out) {
    __shared__ float sred[4];
    __shared__ float swt[CAP];
    __shared__ int   sidx[CAP];
    __shared__ int   scnt;
    const int t = threadIdx.x, lane = t & 63, wave = t >> 6;

    // global max over 1024 block maxes
    float m = fmaxf(fmaxf(bmax[t], bmax[t + 256]), fmaxf(bmax[t + 512], bmax[t + 768]));
#pragma unroll
    for (int off = 32; off > 0; off >>= 1) m = fmaxf(m, __shfl_down(m, off, 64));
    if (lane == 0) sred[wave] = m;
    __syncthreads();
    m = fmaxf(fmaxf(sred[0], sred[1]), fmaxf(sred[2], sred[3]));
    __syncthreads();
    // global denom via rescaled block sums
    float s = bsum[t]       * __expf(bmax[t]       - m)
            + bsum[t + 256] * __expf(bmax[t + 256] - m)
            + bsum[t + 512] * __expf(bmax[t + 512] - m)
            + bsum[t + 768] * __expf(bmax[t + 768] - m);
#pragma unroll
    for (int off = 32; off > 0; off >>= 1) s += __shfl_down(s, off, 64);
    if (lane == 0) sred[wave] = s;
    if (t == 0) scnt = 0;
    __syncthreads();
    const float inv = 1.f / (sred[0] + sred[1] + sred[2] + sred[3]);

    // scan all 16384 scores (64 KB, L2-hot), collect surviving rows
    for (int i = t; i < SEQ_LEN; i += 256) {
        const float w = __expf(scores[i] - m) * inv;
        if (w > WTHR) {
            const int p = atomicAdd(&scnt, 1);
            if (p < CAP) { swt[p] = w; sidx[p] = i; }
        }
    }
    __syncthreads();
    const int n = scnt;

    const float4* e4 = (const float4*)enc;
    float4 c0 = {0.f, 0.f, 0.f, 0.f}, c1 = {0.f, 0.f, 0.f, 0.f};
    if (n <= CAP) {
        // 2-wide software pipeline: 4 loads in flight per step, halves latency chain
        int j = 0;
        for (; j + 1 < n; j += 2) {
            const float wA = swt[j],     wB = swt[j + 1];
            const size_t rA = (size_t)sidx[j]     * (ENC_H / 4);
            const size_t rB = (size_t)sidx[j + 1] * (ENC_H / 4);
            const float4 xA = e4[rA + t], yA = e4[rA + t + 256];
            const float4 xB = e4[rB + t], yB = e4[rB + t + 256];
            c0.x += wA * xA.x + wB * xB.x; c0.y += wA * xA.y + wB * xB.y;
            c0.z += wA * xA.z + wB * xB.z; c0.w += wA * xA.w + wB * xB.w;
            c1.x += wA * yA.x + wB * yB.x; c1.y += wA * yA.y + wB * yB.y;
            c1.z += wA * yA.z + wB * yB.z; c1.w += wA * yA.w + wB * yB.w;
        }
        if (j < n) {
            const float w = swt[j];
            const size_t r = (size_t)sidx[j] * (ENC_H / 4);
            const float4 x = e4[r + t], y = e4[r + t + 256];
            c0.x += w * x.x; c0.y += w * x.y; c0.z += w * x.z; c0.w += w * x.w;
            c1.x += w * y.x; c1.y += w * y.y; c1.z += w * y.z; c1.w += w * y.w;
        }
    } else {
        // overflow fallback (never expected for this input): dense, correct, slow
        for (int rr = 0; rr < SEQ_LEN; ++rr) {
            const float w = __expf(scores[rr] - m) * inv;
            if (w <= WTHR) continue;
            const size_t r = (size_t)rr * (ENC_H / 4);
            const float4 x = e4[r + t], y = e4[r + t + 256];
            c0.x += w * x.x; c0.y += w * x.y; c0.z += w * x.z; c0.w += w * x.w;
            c1.x += w * y.x; c1.y += w * y.y; c1.z += w * y.z; c1.w += w * y.w;
        }
    }
    out[4 * t + 0] = c0.x; out[4 * t + 1] = c0.y;
    out[4 * t + 2] = c0.z; out[4 * t + 3] = c0.w;
    out[4 * (t + 256) + 0] = c1.x; out[4 * (t + 256) + 1] = c1.y;
    out[4 * (t + 256) + 2] = c1.z; out[4 * (t + 256) + 3] = c1.w;
}

extern "C" void kernel_launch(void* const* d_in, const int* in_sizes, int n_in,
                              void* d_out, int out_size, void* d_ws, size_t ws_size,
                              hipStream_t stream) {
    const float* enc = (const float*)d_in[0];   // [16384, 2048]
    const float* dec = (const float*)d_in[1];   // [1, 2048]
    const float* W   = (const float*)d_in[2];   // [2048, 2048]
    float* out = (float*)d_out;                 // [1, 2048]

    float* ws     = (float*)d_ws;
    float* v      = ws;                  // 2048
    float* scores = v + ENC_H;           // 16384
    float* bmax   = scores + SEQ_LEN;    // 1024
    float* bsum   = bmax + NB_SC;        // 1024

    k_wv      <<<ENC_H, 256, 0, stream>>>(W, dec, v);
    k_scores  <<<NB_SC, 256, 0, stream>>>(enc, v, scores, bmax, bsum);
    k_finalize<<<1,     256, 0, stream>>>(enc, scores, bmax, bsum, out);
}